// Round 1
// baseline (617.191 us; speedup 1.0000x reference)
//
#include <hip/hip_runtime.h>
#include <hip/hip_bf16.h>

// Problem constants (B=8192, D=128 from reference setup_inputs)
constexpr int Bh = 8192;
constexpr int Nn = 16384;   // 2*B
constexpr int Dd = 128;
constexpr float EPS = 1e-8f;

constexpr int CSPLIT = 16;                       // column splits for occupancy
constexpr int COLS_PER_BLOCK = Nn / CSPLIT;      // 1024
constexpr int TILE_COLS = 128;                   // LDS-staged column tile
constexpr int NCT = COLS_PER_BLOCK / TILE_COLS;  // 8
constexpr int ROWS_PER_BLOCK = 256;              // 4 waves * 64 rows
constexpr int ROWS_PER_WAVE = 64;                // 4 accumulator sets of 16
constexpr int LDS_STRIDE = 136;                  // 128 bf16 + 8 pad (272B rows -> bank-friendly)

typedef short bf16x8 __attribute__((ext_vector_type(8)));
typedef float f32x4 __attribute__((ext_vector_type(4)));

// ---- Kernel 1: fp32 -> bf16 (scaled by sqrt(2) so MFMA dot == sim/tau), zero rowsum ----
__global__ __launch_bounds__(256) void convert_kernel(const float4* __restrict__ za,
                                                      const float4* __restrict__ zb,
                                                      ushort* __restrict__ z,
                                                      float* __restrict__ rowsum) {
    const int t = blockIdx.x * 256 + threadIdx.x;        // 0 .. 524287
    constexpr int Q = (Bh * Dd) / 4;                     // 262144 float4 per input
    const float s = 1.41421356237f;                      // sqrt(1/tau) = sqrt(2)
    float4 v = (t < Q) ? za[t] : zb[t - Q];
    union { ushort4 u4; __hip_bfloat16 h[4]; } cv;
    cv.h[0] = __float2bfloat16(v.x * s);
    cv.h[1] = __float2bfloat16(v.y * s);
    cv.h[2] = __float2bfloat16(v.z * s);
    cv.h[3] = __float2bfloat16(v.w * s);
    ((ushort4*)z)[t] = cv.u4;
    if (t < Nn) rowsum[t] = 0.f;
}

// ---- Kernel 2: tiled MFMA sim + fused softplus / diag-zero / pos-extract / row-sums ----
__global__ __launch_bounds__(256, 4) void main_kernel(const ushort* __restrict__ z,
                                                      float* __restrict__ rowsum,
                                                      float* __restrict__ pospair) {
    __shared__ ushort lds[TILE_COLS * LDS_STRIDE];   // 34816 B

    const int wave = threadIdx.x >> 6;
    const int lane = threadIdx.x & 63;
    const int q = lane >> 4;        // quad: 0..3
    const int c = lane & 15;        // 0..15

    const int rowW = blockIdx.x * ROWS_PER_BLOCK + wave * ROWS_PER_WAVE;
    const int col0 = blockIdx.y * COLS_PER_BLOCK;

    // A fragments: 4 row-sets x 4 k-tiles, each lane holds A[m=c][k=q*8+j]
    bf16x8 afrag[4][4];
#pragma unroll
    for (int s = 0; s < 4; ++s) {
        const ushort* ap = z + (size_t)(rowW + s * 16 + c) * Dd;
#pragma unroll
        for (int kt = 0; kt < 4; ++kt)
            afrag[s][kt] = *(const bf16x8*)(ap + kt * 32 + q * 8);
    }

    float rs[4][4];
#pragma unroll
    for (int s = 0; s < 4; ++s)
#pragma unroll
        for (int r = 0; r < 4; ++r) rs[s][r] = 0.f;

    for (int ct = 0; ct < NCT; ++ct) {
        const int cbase = col0 + ct * TILE_COLS;
        __syncthreads();   // protect LDS reuse from previous iteration
        // stage 128 cols x 128 k of bf16 into LDS (padded stride)
#pragma unroll
        for (int it = 0; it < 8; ++it) {
            int chunk = it * 256 + threadIdx.x;       // 0..2047 chunks of 16B
            int ccol = chunk >> 4;                    // 16 chunks per 128-elem row
            int ko = (chunk & 15) * 8;
            uint4 val = *(const uint4*)(z + (size_t)(cbase + ccol) * Dd + ko);
            *(uint4*)(&lds[ccol * LDS_STRIDE + ko]) = val;
        }
        __syncthreads();

#pragma unroll
        for (int st = 0; st < 8; ++st) {
            f32x4 acc[4] = {{0.f,0.f,0.f,0.f},{0.f,0.f,0.f,0.f},{0.f,0.f,0.f,0.f},{0.f,0.f,0.f,0.f}};
#pragma unroll
            for (int kt = 0; kt < 4; ++kt) {
                bf16x8 bfrag = *(const bf16x8*)(&lds[(st * 16 + c) * LDS_STRIDE + kt * 32 + q * 8]);
#pragma unroll
                for (int s = 0; s < 4; ++s)
                    acc[s] = __builtin_amdgcn_mfma_f32_16x16x32_bf16(afrag[s][kt], bfrag, acc[s], 0, 0, 0);
            }
            const int gc0 = cbase + st * 16;
#pragma unroll
            for (int s = 0; s < 4; ++s) {
                const int R = rowW + s * 16;
                // diag only possible if col-tile == row-tile; pos pair iff col-tile == row-tile ^ 8192
                const bool special = (gc0 == R) || (gc0 == (R ^ Bh));
                if (!special) {
#pragma unroll
                    for (int r = 0; r < 4; ++r) {
                        float x = acc[s][r];
                        float e = __expf(-fabsf(x));
                        float sp = fmaxf(x, 0.f) + __logf(1.f + e);
                        rs[s][r] += sp;
                    }
                } else {
#pragma unroll
                    for (int r = 0; r < 4; ++r) {
                        int grow = R + q * 4 + r;
                        int gcol = gc0 + c;
                        float x = acc[s][r];
                        float e = __expf(-fabsf(x));
                        float sp = fmaxf(x, 0.f) + __logf(1.f + e);
                        if (gcol == grow) sp = 0.f;          // zero self-similarity
                        rs[s][r] += sp;
                        if (gcol == (grow ^ Bh)) pospair[grow] = sp;  // (i+B)%N == i^B
                    }
                }
            }
        }
    }

    // reduce row-sums across the 16 column-lanes of each quad group, then atomicAdd
#pragma unroll
    for (int s = 0; s < 4; ++s) {
#pragma unroll
        for (int r = 0; r < 4; ++r) {
            float v = rs[s][r];
            v += __shfl_xor(v, 1);
            v += __shfl_xor(v, 2);
            v += __shfl_xor(v, 4);
            v += __shfl_xor(v, 8);
            if (c == 0) atomicAdd(&rowsum[rowW + s * 16 + q * 4 + r], v);
        }
    }
}

// ---- Kernel 3: final loss ----
__global__ __launch_bounds__(256) void finalize_kernel(const float* __restrict__ rowsum,
                                                       const float* __restrict__ pospair,
                                                       float* __restrict__ out) {
    __shared__ float red[4];
    float acc = 0.f;
    for (int i = threadIdx.x; i < Nn; i += 256) {
        float denom = fmaxf(rowsum[i], EPS);
        float sp = fmaxf(pospair[i], EPS);
        acc += logf(sp) - logf(denom);
    }
#pragma unroll
    for (int m = 1; m < 64; m <<= 1) acc += __shfl_xor(acc, m);
    if ((threadIdx.x & 63) == 0) red[threadIdx.x >> 6] = acc;
    __syncthreads();
    if (threadIdx.x == 0) {
        out[0] = -(red[0] + red[1] + red[2] + red[3]) / (float)Nn;
    }
}

extern "C" void kernel_launch(void* const* d_in, const int* in_sizes, int n_in,
                              void* d_out, int out_size, void* d_ws, size_t ws_size,
                              hipStream_t stream) {
    const float* za = (const float*)d_in[0];
    const float* zb = (const float*)d_in[1];

    // workspace layout: z_bf16 (4 MB) | rowsum (64 KB) | pospair (64 KB)
    ushort* z = (ushort*)d_ws;
    float* rowsum = (float*)((char*)d_ws + (size_t)Nn * Dd * 2);
    float* pospair = rowsum + Nn;
    float* out = (float*)d_out;

    convert_kernel<<<2048, 256, 0, stream>>>((const float4*)za, (const float4*)zb, z, rowsum);
    dim3 grid(Nn / ROWS_PER_BLOCK, CSPLIT);   // (64, 16)
    main_kernel<<<grid, 256, 0, stream>>>(z, rowsum, pospair);
    finalize_kernel<<<1, 256, 0, stream>>>(rowsum, pospair, out);
}

// Round 2
// 381.417 us; speedup vs baseline: 1.6182x; 1.6182x over previous
//
#include <hip/hip_runtime.h>
#include <hip/hip_bf16.h>

// Problem constants (B=8192, D=128 from reference setup_inputs)
constexpr int Bh = 8192;
constexpr int Nn = 16384;   // 2*B
constexpr int Dd = 128;
constexpr float EPS = 1e-8f;

constexpr int CSPLIT = 16;                       // column splits for occupancy
constexpr int COLS_PER_BLOCK = Nn / CSPLIT;      // 1024
constexpr int TILE_COLS = 128;                   // LDS-staged column tile
constexpr int NCT = COLS_PER_BLOCK / TILE_COLS;  // 8
constexpr int ROWS_PER_BLOCK = 256;              // 4 waves * 64 rows
constexpr int ROWS_PER_WAVE = 64;                // 4 accumulator sets of 16
constexpr int LDS_STRIDE = 136;                  // 128 bf16 + 8 pad (272B rows -> bank-friendly)

typedef short bf16x8 __attribute__((ext_vector_type(8)));
typedef float f32x4 __attribute__((ext_vector_type(4)));

// ---- Kernel 1: fp32 -> bf16 (scaled by sqrt(2) so MFMA dot == sim/tau), zero rowsum ----
__global__ __launch_bounds__(256) void convert_kernel(const float4* __restrict__ za,
                                                      const float4* __restrict__ zb,
                                                      ushort* __restrict__ z,
                                                      float* __restrict__ rowsum) {
    const int t = blockIdx.x * 256 + threadIdx.x;        // 0 .. 524287
    constexpr int Q = (Bh * Dd) / 4;                     // 262144 float4 per input
    const float s = 1.41421356237f;                      // sqrt(1/tau) = sqrt(2)
    float4 v = (t < Q) ? za[t] : zb[t - Q];
    union { ushort4 u4; __hip_bfloat16 h[4]; } cv;
    cv.h[0] = __float2bfloat16(v.x * s);
    cv.h[1] = __float2bfloat16(v.y * s);
    cv.h[2] = __float2bfloat16(v.z * s);
    cv.h[3] = __float2bfloat16(v.w * s);
    ((ushort4*)z)[t] = cv.u4;
    if (t < Nn) rowsum[t] = 0.f;
}

// ---- Kernel 2: tiled MFMA sim + fused softplus / diag-zero / pos-extract / row-sums ----
// __launch_bounds__(256): NO min-waves arg — (256,4) clamped the allocator to the
// 64-VGPR occupancy bucket (per-SIMD pool ~512 regs) and spilled afrag/acc to
// scratch: 2 GB/dispatch HBM traffic, 554 us. Register plan needs ~140 VGPRs.
__global__ __launch_bounds__(256) void main_kernel(const ushort* __restrict__ z,
                                                   float* __restrict__ rowsum,
                                                   float* __restrict__ pospair) {
    __shared__ ushort lds[TILE_COLS * LDS_STRIDE];   // 34816 B

    const int wave = threadIdx.x >> 6;
    const int lane = threadIdx.x & 63;
    const int q = lane >> 4;        // quad: 0..3
    const int c = lane & 15;        // 0..15

    const int rowW = blockIdx.x * ROWS_PER_BLOCK + wave * ROWS_PER_WAVE;
    const int col0 = blockIdx.y * COLS_PER_BLOCK;

    // A fragments: 4 row-sets x 4 k-tiles, each lane holds A[m=c][k=q*8+j]
    bf16x8 afrag[4][4];
#pragma unroll
    for (int s = 0; s < 4; ++s) {
        const ushort* ap = z + (size_t)(rowW + s * 16 + c) * Dd;
#pragma unroll
        for (int kt = 0; kt < 4; ++kt)
            afrag[s][kt] = *(const bf16x8*)(ap + kt * 32 + q * 8);
    }

    float rs[4][4];
#pragma unroll
    for (int s = 0; s < 4; ++s)
#pragma unroll
        for (int r = 0; r < 4; ++r) rs[s][r] = 0.f;

    for (int ct = 0; ct < NCT; ++ct) {
        const int cbase = col0 + ct * TILE_COLS;
        __syncthreads();   // protect LDS reuse from previous iteration
        // stage 128 cols x 128 k of bf16 into LDS (padded stride)
#pragma unroll
        for (int it = 0; it < 8; ++it) {
            int chunk = it * 256 + threadIdx.x;       // 0..2047 chunks of 16B
            int ccol = chunk >> 4;                    // 16 chunks per 128-elem row
            int ko = (chunk & 15) * 8;
            uint4 val = *(const uint4*)(z + (size_t)(cbase + ccol) * Dd + ko);
            *(uint4*)(&lds[ccol * LDS_STRIDE + ko]) = val;
        }
        __syncthreads();

#pragma unroll
        for (int st = 0; st < 8; ++st) {
            f32x4 acc[4] = {{0.f,0.f,0.f,0.f},{0.f,0.f,0.f,0.f},{0.f,0.f,0.f,0.f},{0.f,0.f,0.f,0.f}};
#pragma unroll
            for (int kt = 0; kt < 4; ++kt) {
                bf16x8 bfrag = *(const bf16x8*)(&lds[(st * 16 + c) * LDS_STRIDE + kt * 32 + q * 8]);
#pragma unroll
                for (int s = 0; s < 4; ++s)
                    acc[s] = __builtin_amdgcn_mfma_f32_16x16x32_bf16(afrag[s][kt], bfrag, acc[s], 0, 0, 0);
            }
            const int gc0 = cbase + st * 16;
#pragma unroll
            for (int s = 0; s < 4; ++s) {
                const int R = rowW + s * 16;
                // diag only possible if col-tile == row-tile; pos pair iff col-tile == row-tile ^ 8192
                const bool special = (gc0 == R) || (gc0 == (R ^ Bh));
                if (!special) {
#pragma unroll
                    for (int r = 0; r < 4; ++r) {
                        float x = acc[s][r];
                        float e = __expf(-fabsf(x));
                        float sp = fmaxf(x, 0.f) + __logf(1.f + e);
                        rs[s][r] += sp;
                    }
                } else {
#pragma unroll
                    for (int r = 0; r < 4; ++r) {
                        int grow = R + q * 4 + r;
                        int gcol = gc0 + c;
                        float x = acc[s][r];
                        float e = __expf(-fabsf(x));
                        float sp = fmaxf(x, 0.f) + __logf(1.f + e);
                        if (gcol == grow) sp = 0.f;          // zero self-similarity
                        rs[s][r] += sp;
                        if (gcol == (grow ^ Bh)) pospair[grow] = sp;  // (i+B)%N == i^B
                    }
                }
            }
        }
    }

    // reduce row-sums across the 16 column-lanes of each quad group, then atomicAdd
#pragma unroll
    for (int s = 0; s < 4; ++s) {
#pragma unroll
        for (int r = 0; r < 4; ++r) {
            float v = rs[s][r];
            v += __shfl_xor(v, 1);
            v += __shfl_xor(v, 2);
            v += __shfl_xor(v, 4);
            v += __shfl_xor(v, 8);
            if (c == 0) atomicAdd(&rowsum[rowW + s * 16 + q * 4 + r], v);
        }
    }
}

// ---- Kernel 3: final loss ----
__global__ __launch_bounds__(256) void finalize_kernel(const float* __restrict__ rowsum,
                                                       const float* __restrict__ pospair,
                                                       float* __restrict__ out) {
    __shared__ float red[4];
    float acc = 0.f;
    for (int i = threadIdx.x; i < Nn; i += 256) {
        float denom = fmaxf(rowsum[i], EPS);
        float sp = fmaxf(pospair[i], EPS);
        acc += logf(sp) - logf(denom);
    }
#pragma unroll
    for (int m = 1; m < 64; m <<= 1) acc += __shfl_xor(acc, m);
    if ((threadIdx.x & 63) == 0) red[threadIdx.x >> 6] = acc;
    __syncthreads();
    if (threadIdx.x == 0) {
        out[0] = -(red[0] + red[1] + red[2] + red[3]) / (float)Nn;
    }
}

extern "C" void kernel_launch(void* const* d_in, const int* in_sizes, int n_in,
                              void* d_out, int out_size, void* d_ws, size_t ws_size,
                              hipStream_t stream) {
    const float* za = (const float*)d_in[0];
    const float* zb = (const float*)d_in[1];

    // workspace layout: z_bf16 (4 MB) | rowsum (64 KB) | pospair (64 KB)
    ushort* z = (ushort*)d_ws;
    float* rowsum = (float*)((char*)d_ws + (size_t)Nn * Dd * 2);
    float* pospair = rowsum + Nn;
    float* out = (float*)d_out;

    convert_kernel<<<2048, 256, 0, stream>>>((const float4*)za, (const float4*)zb, z, rowsum);
    dim3 grid(Nn / ROWS_PER_BLOCK, CSPLIT);   // (64, 16)
    main_kernel<<<grid, 256, 0, stream>>>(z, rowsum, pospair);
    finalize_kernel<<<1, 256, 0, stream>>>(rowsum, pospair, out);
}

// Round 3
// 304.222 us; speedup vs baseline: 2.0288x; 1.2537x over previous
//
#include <hip/hip_runtime.h>
#include <hip/hip_bf16.h>

// Problem constants (B=8192, D=128 from reference setup_inputs)
constexpr int Bh = 8192;
constexpr int Nn = 16384;   // 2*B
constexpr int Dd = 128;
constexpr float EPS = 1e-8f;

constexpr int TILE_COLS = 128;                   // LDS-staged column tile (one per block)
constexpr int ROWS_PER_BLOCK = 256;              // 4 waves * 64 rows
constexpr int LDS_STRIDE = 136;                  // 128 bf16 + 8 pad

typedef short bf16x8 __attribute__((ext_vector_type(8)));
typedef float f32x4 __attribute__((ext_vector_type(4)));

// ---- Kernel 1: fp32 -> bf16 (scaled by sqrt(2) so MFMA dot == sim/tau), zero rowsum ----
__global__ __launch_bounds__(256) void convert_kernel(const float4* __restrict__ za,
                                                      const float4* __restrict__ zb,
                                                      ushort* __restrict__ z,
                                                      float* __restrict__ rowsum) {
    const int t = blockIdx.x * 256 + threadIdx.x;        // 0 .. 524287
    constexpr int Q = (Bh * Dd) / 4;                     // 262144 float4 per input
    const float s = 1.41421356237f;                      // sqrt(1/tau) = sqrt(2)
    float4 v = (t < Q) ? za[t] : zb[t - Q];
    union { ushort4 u4; __hip_bfloat16 h[4]; } cv;
    cv.h[0] = __float2bfloat16(v.x * s);
    cv.h[1] = __float2bfloat16(v.y * s);
    cv.h[2] = __float2bfloat16(v.z * s);
    cv.h[3] = __float2bfloat16(v.w * s);
    ((ushort4*)z)[t] = cv.u4;
    if (t < Nn) rowsum[t] = 0.f;
}

// ---- Kernel 2: upper-triangle tiles only (sp is symmetric: rowsum == colsum).
// Grid (64 row-blocks of 256) x (128 col-tiles of 128); block exits if col-tile
// entirely below the diagonal. Off-diagonal tiles credit BOTH rowsum[rows]
// (register accumulate) and rowsum[cols] (shuffle col-reduce -> LDS ds_add_f32
// -> one global atomic per col). Diagonal 128x128 tiles: rowsum only (tile is
// symmetric, col-sums would double count). Positive pair j = i^8192 lives in
// tile (rt, rt^64), always upper triangle; pospair[i] == pospair[i^B] so only
// B entries are written and finalize reads pp[i & (B-1)].
__global__ __launch_bounds__(256) void main_kernel(const ushort* __restrict__ z,
                                                   float* __restrict__ rowsum,
                                                   float* __restrict__ pospair) {
    __shared__ ushort lds[TILE_COLS * LDS_STRIDE];   // 34816 B
    __shared__ float lds_cs[TILE_COLS];              // per-block col-sum accumulators

    const int b  = blockIdx.x;     // 256-row block: rows [256b, 256b+256)
    const int ct = blockIdx.y;     // 128-col tile:  cols [128ct, 128ct+128)
    if (ct < 2 * b) return;        // entirely below diagonal -> transpose covers it

    const int wave = threadIdx.x >> 6;
    const int lane = threadIdx.x & 63;
    const int q = lane >> 4;        // quad: 0..3
    const int c = lane & 15;        // 0..15

    const int R0 = b << 8;
    const int C0 = ct << 7;
    const int rowW = R0 + wave * 64;
    const int rt = rowW >> 7;              // 128-row tile index of this wave
    const bool skip = (ct < rt);           // lower-triangle half-block: idle compute
    const bool diag = (ct == rt);

    // A fragments: 4 row-sets x 4 k-tiles, each lane holds A[m=c][k=q*8+j]
    bf16x8 afrag[4][4];
    if (!skip) {
#pragma unroll
        for (int s = 0; s < 4; ++s) {
            const ushort* ap = z + (size_t)(rowW + s * 16 + c) * Dd;
#pragma unroll
            for (int kt = 0; kt < 4; ++kt)
                afrag[s][kt] = *(const bf16x8*)(ap + kt * 32 + q * 8);
        }
    }

    // stage 128 cols x 128 k of bf16 into LDS (padded stride); zero col-sums
    if (threadIdx.x < TILE_COLS) lds_cs[threadIdx.x] = 0.f;
#pragma unroll
    for (int it = 0; it < 8; ++it) {
        int chunk = it * 256 + threadIdx.x;       // 0..2047 chunks of 16B
        int ccol = chunk >> 4;                    // 16 chunks per 128-elem row
        int ko = (chunk & 15) * 8;
        uint4 val = *(const uint4*)(z + (size_t)(C0 + ccol) * Dd + ko);
        *(uint4*)(&lds[ccol * LDS_STRIDE + ko]) = val;
    }
    __syncthreads();

    if (!skip) {
        float rs[4][4];
#pragma unroll
        for (int s = 0; s < 4; ++s)
#pragma unroll
            for (int r = 0; r < 4; ++r) rs[s][r] = 0.f;

#pragma unroll
        for (int st = 0; st < 8; ++st) {
            f32x4 acc[4] = {{0.f,0.f,0.f,0.f},{0.f,0.f,0.f,0.f},{0.f,0.f,0.f,0.f},{0.f,0.f,0.f,0.f}};
#pragma unroll
            for (int kt = 0; kt < 4; ++kt) {
                bf16x8 bfrag = *(const bf16x8*)(&lds[(st * 16 + c) * LDS_STRIDE + kt * 32 + q * 8]);
#pragma unroll
                for (int s = 0; s < 4; ++s)
                    acc[s] = __builtin_amdgcn_mfma_f32_16x16x32_bf16(afrag[s][kt], bfrag, acc[s], 0, 0, 0);
            }
            const int gc0 = C0 + st * 16;
#pragma unroll
            for (int s = 0; s < 4; ++s) {
                const int R = rowW + s * 16;
                float sp[4];
#pragma unroll
                for (int r = 0; r < 4; ++r) {
                    float x = acc[s][r];
                    float e = __expf(-fabsf(x));
                    sp[r] = fmaxf(x, 0.f) + __logf(1.f + e);
                }
                if (diag && gc0 == R) {           // zero self-similarity
#pragma unroll
                    for (int r = 0; r < 4; ++r)
                        if (c == q * 4 + r) sp[r] = 0.f;
                }
                const bool pos = (gc0 == (R ^ Bh));   // positive-pair subtile
#pragma unroll
                for (int r = 0; r < 4; ++r) {
                    rs[s][r] += sp[r];
                    if (pos && c == q * 4 + r) pospair[R + q * 4 + r] = sp[r];
                }
                if (!diag) {                      // col-sum credit (transpose rows)
                    float t = sp[0] + sp[1] + sp[2] + sp[3];
                    t += __shfl_xor(t, 16);
                    t += __shfl_xor(t, 32);
                    if (lane < 16) atomicAdd(&lds_cs[st * 16 + c], t);
                }
            }
        }

        // reduce row-sums across the 16 column-lanes, then one atomic per row
#pragma unroll
        for (int s = 0; s < 4; ++s) {
#pragma unroll
            for (int r = 0; r < 4; ++r) {
                float v = rs[s][r];
                v += __shfl_xor(v, 1);
                v += __shfl_xor(v, 2);
                v += __shfl_xor(v, 4);
                v += __shfl_xor(v, 8);
                if (c == 0) atomicAdd(&rowsum[rowW + s * 16 + q * 4 + r], v);
            }
        }
    }

    __syncthreads();
    if (threadIdx.x < TILE_COLS) {
        float v = lds_cs[threadIdx.x];
        if (v != 0.f) atomicAdd(&rowsum[C0 + threadIdx.x], v);
    }
}

// ---- Kernel 3: final loss ----
__global__ __launch_bounds__(256) void finalize_kernel(const float* __restrict__ rowsum,
                                                       const float* __restrict__ pospair,
                                                       float* __restrict__ out) {
    __shared__ float red[4];
    float acc = 0.f;
    for (int i = threadIdx.x; i < Nn; i += 256) {
        float denom = fmaxf(rowsum[i], EPS);
        float sp = fmaxf(pospair[i & (Bh - 1)], EPS);   // pospair[i] == pospair[i^B]
        acc += logf(sp) - logf(denom);
    }
#pragma unroll
    for (int m = 1; m < 64; m <<= 1) acc += __shfl_xor(acc, m);
    if ((threadIdx.x & 63) == 0) red[threadIdx.x >> 6] = acc;
    __syncthreads();
    if (threadIdx.x == 0) {
        out[0] = -(red[0] + red[1] + red[2] + red[3]) / (float)Nn;
    }
}

extern "C" void kernel_launch(void* const* d_in, const int* in_sizes, int n_in,
                              void* d_out, int out_size, void* d_ws, size_t ws_size,
                              hipStream_t stream) {
    const float* za = (const float*)d_in[0];
    const float* zb = (const float*)d_in[1];

    // workspace layout: z_bf16 (4 MB) | rowsum (64 KB) | pospair (32 KB used)
    ushort* z = (ushort*)d_ws;
    float* rowsum = (float*)((char*)d_ws + (size_t)Nn * Dd * 2);
    float* pospair = rowsum + Nn;
    float* out = (float*)d_out;

    convert_kernel<<<2048, 256, 0, stream>>>((const float4*)za, (const float4*)zb, z, rowsum);
    dim3 grid(Nn / ROWS_PER_BLOCK, Nn / TILE_COLS);   // (64, 128), ~half exit early
    main_kernel<<<grid, 256, 0, stream>>>(z, rowsum, pospair);
    finalize_kernel<<<1, 256, 0, stream>>>(rowsum, pospair, out);
}

// Round 4
// 228.746 us; speedup vs baseline: 2.6982x; 1.3300x over previous
//
#include <hip/hip_runtime.h>
#include <hip/hip_bf16.h>

// Problem constants (B=8192, D=128 from reference setup_inputs)
constexpr int Bh = 8192;
constexpr int Nn = 16384;   // 2*B
constexpr int Dd = 128;
constexpr float EPS = 1e-8f;
constexpr float LN2 = 0.69314718056f;

constexpr int TILE_COLS = 128;     // LDS-staged column tile
constexpr int LDS_STRIDE = 136;    // 128 bf16 + 8 pad
constexpr int K_TILES = 4;         // col-tiles per block
constexpr int N_TILES = 4160;      // #upper-triangle 256x128 tiles = sum_b (128-2b)
constexpr int N_BLOCKS = N_TILES / K_TILES;   // 1040, exact

typedef short bf16x8 __attribute__((ext_vector_type(8)));
typedef float f32x4 __attribute__((ext_vector_type(4)));

// ---- Kernel 1: fp32 -> bf16, scaled by sqrt(2*log2e) so MFMA dot == sim/tau*log2e ----
__global__ __launch_bounds__(256) void convert_kernel(const float4* __restrict__ za,
                                                      const float4* __restrict__ zb,
                                                      ushort* __restrict__ z,
                                                      float* __restrict__ rowsum) {
    const int t = blockIdx.x * 256 + threadIdx.x;        // 0 .. 524287
    constexpr int Q = (Bh * Dd) / 4;                     // 262144 float4 per input
    const float SCL = 1.69864363f;                       // sqrt(2 * 1.4426950409)
    float4 v = (t < Q) ? za[t] : zb[t - Q];
    union { ushort4 u4; __hip_bfloat16 h[4]; } cv;
    cv.h[0] = __float2bfloat16(v.x * SCL);
    cv.h[1] = __float2bfloat16(v.y * SCL);
    cv.h[2] = __float2bfloat16(v.z * SCL);
    cv.h[3] = __float2bfloat16(v.w * SCL);
    ((ushort4*)z)[t] = cv.u4;
    if (t < Nn) rowsum[t] = 0.f;
}

// row-credit flush: reduce rs over the 16 col-lanes, one atomic per row (log2 domain)
__device__ __forceinline__ void flush_rs(float* __restrict__ rowsum, int rowW,
                                         float (&rs)[4][4], int q, int c) {
#pragma unroll
    for (int s = 0; s < 4; ++s)
#pragma unroll
        for (int r = 0; r < 4; ++r) {
            float v = rs[s][r];
            v += __shfl_xor(v, 1);
            v += __shfl_xor(v, 2);
            v += __shfl_xor(v, 4);
            v += __shfl_xor(v, 8);
            if (c == 0) atomicAdd(&rowsum[rowW + s * 16 + q * 4 + r], v);
            rs[s][r] = 0.f;
        }
}

// ---- Kernel 2: symmetric upper-triangle, 4 equal tiles per block ----
// Tile g in [0,4160) maps to row-block b (256 rows) / col-tile ct (128 cols) via
// cum(b) = b*(129-b);  ct = 2b + (g - cum(b)), always ct >= 2b (upper triangle).
// Off-diag wave-tiles credit rows (register rs) AND cols (register csum -> 2
// shuffles + global atomic per tile); diagonal 128-tiles credit rows only.
// All softplus sums are in log2 domain (z pre-scaled by sqrt(2*log2e)); finalize
// multiplies by ln2.
__global__ __launch_bounds__(256) void main_kernel(const ushort* __restrict__ z,
                                                   float* __restrict__ rowsum,
                                                   float* __restrict__ pospair) {
    __shared__ ushort lds[TILE_COLS * LDS_STRIDE];   // 34816 B -> 4 blocks/CU by LDS

    const int wave = threadIdx.x >> 6;
    const int lane = threadIdx.x & 63;
    const int q = lane >> 4;        // quad: 0..3
    const int c = lane & 15;        // 0..15
    const int g0 = blockIdx.x * K_TILES;

    bf16x8 afrag[4][4];
    float rs[4][4];
    float csum[8];
    int cur_b = -1;
    int rowW = 0;

#pragma unroll
    for (int s = 0; s < 4; ++s)
#pragma unroll
        for (int r = 0; r < 4; ++r) rs[s][r] = 0.f;
#pragma unroll
    for (int st = 0; st < 8; ++st) csum[st] = 0.f;

    for (int j = 0; j < K_TILES; ++j) {
        const int g = g0 + j;
        // row-block from g: b = floor((129 - sqrt(129^2 - 4g))/2), integer fixup
        int b = (int)((129.0f - sqrtf((float)(16641 - 4 * g))) * 0.5f);
        b = b < 0 ? 0 : (b > 63 ? 63 : b);
        while (b * (129 - b) > g) --b;
        while ((b + 1) * (128 - b) <= g) ++b;
        const int ct = 2 * b + (g - b * (129 - b));
        const int C0 = ct << 7;

        if (j) __syncthreads();   // previous tile's compute done before restaging
        // stage B tile: 128 cols x 128 k bf16 (padded stride)
#pragma unroll
        for (int it = 0; it < 8; ++it) {
            int chunk = it * 256 + threadIdx.x;       // 2048 chunks of 16B
            int ccol = chunk >> 4;
            int ko = (chunk & 15) * 8;
            uint4 val = *(const uint4*)(z + (size_t)(C0 + ccol) * Dd + ko);
            *(uint4*)(&lds[ccol * LDS_STRIDE + ko]) = val;
        }
        // A fragments (global loads overlap staging; no LDS hazard)
        if (b != cur_b) {
            if (cur_b >= 0) flush_rs(rowsum, rowW, rs, q, c);  // rows of previous block
            cur_b = b;
            rowW = (b << 8) + wave * 64;
#pragma unroll
            for (int s = 0; s < 4; ++s) {
                const ushort* ap = z + (size_t)(rowW + s * 16 + c) * Dd;
#pragma unroll
                for (int kt = 0; kt < 4; ++kt)
                    afrag[s][kt] = *(const bf16x8*)(ap + kt * 32 + q * 8);
            }
        }
        __syncthreads();

        const int rt = rowW >> 7;             // this wave's 128-row tile
        const bool skip = (ct < rt);          // below diagonal: mirror covers it
        const bool diag = (ct == rt);
        if (!skip) {
#pragma unroll
            for (int st = 0; st < 8; ++st) {
                f32x4 acc[4] = {{0.f,0.f,0.f,0.f},{0.f,0.f,0.f,0.f},{0.f,0.f,0.f,0.f},{0.f,0.f,0.f,0.f}};
#pragma unroll
                for (int kt = 0; kt < 4; ++kt) {
                    bf16x8 bfrag = *(const bf16x8*)(&lds[(st * 16 + c) * LDS_STRIDE + kt * 32 + q * 8]);
#pragma unroll
                    for (int s = 0; s < 4; ++s)
                        acc[s] = __builtin_amdgcn_mfma_f32_16x16x32_bf16(afrag[s][kt], bfrag, acc[s], 0, 0, 0);
                }
                const int gc0 = C0 + st * 16;
#pragma unroll
                for (int s = 0; s < 4; ++s) {
                    const int R = rowW + s * 16;
                    float sp[4];
#pragma unroll
                    for (int r = 0; r < 4; ++r) {
                        float u = acc[s][r];
                        // softplus in log2 domain: max(u,0) + log2(1 + 2^-|u|)
                        float e = __builtin_amdgcn_exp2f(-fabsf(u));
                        sp[r] = fmaxf(u, 0.f) + __builtin_amdgcn_logf(1.f + e);
                    }
                    if (diag && gc0 == R) {               // zero self-similarity
#pragma unroll
                        for (int r = 0; r < 4; ++r)
                            if (c == q * 4 + r) sp[r] = 0.f;
                    }
                    if (gc0 == (R ^ Bh)) {                // positive-pair subtile (rows<8192)
#pragma unroll
                        for (int r = 0; r < 4; ++r)
                            if (c == q * 4 + r) pospair[R + q * 4 + r] = sp[r];
                    }
#pragma unroll
                    for (int r = 0; r < 4; ++r) rs[s][r] += sp[r];
                    if (!diag) csum[st] += (sp[0] + sp[1]) + (sp[2] + sp[3]);
                }
            }
            if (!diag) {   // col credit: reduce over q (rows), one atomic per col
#pragma unroll
                for (int st = 0; st < 8; ++st) {
                    float v = csum[st];
                    v += __shfl_xor(v, 16);
                    v += __shfl_xor(v, 32);
                    if (lane < 16) atomicAdd(&rowsum[C0 + st * 16 + c], v);
                    csum[st] = 0.f;
                }
            }
        }
    }
    if (cur_b >= 0) flush_rs(rowsum, rowW, rs, q, c);
}

// ---- Kernel 3: final loss (converts log2-domain sums back via ln2) ----
__global__ __launch_bounds__(256) void finalize_kernel(const float* __restrict__ rowsum,
                                                       const float* __restrict__ pospair,
                                                       float* __restrict__ out) {
    __shared__ float red[4];
    float acc = 0.f;
    for (int i = threadIdx.x; i < Nn; i += 256) {
        float denom = fmaxf(LN2 * rowsum[i], EPS);
        float sp = fmaxf(LN2 * pospair[i & (Bh - 1)], EPS);   // pospair[i]==pospair[i^B]
        acc += __logf(sp) - __logf(denom);
    }
#pragma unroll
    for (int m = 1; m < 64; m <<= 1) acc += __shfl_xor(acc, m);
    if ((threadIdx.x & 63) == 0) red[threadIdx.x >> 6] = acc;
    __syncthreads();
    if (threadIdx.x == 0) {
        out[0] = -(red[0] + red[1] + red[2] + red[3]) / (float)Nn;
    }
}

extern "C" void kernel_launch(void* const* d_in, const int* in_sizes, int n_in,
                              void* d_out, int out_size, void* d_ws, size_t ws_size,
                              hipStream_t stream) {
    const float* za = (const float*)d_in[0];
    const float* zb = (const float*)d_in[1];

    // workspace layout: z_bf16 (4 MB) | rowsum (64 KB) | pospair (32 KB used)
    ushort* z = (ushort*)d_ws;
    float* rowsum = (float*)((char*)d_ws + (size_t)Nn * Dd * 2);
    float* pospair = rowsum + Nn;
    float* out = (float*)d_out;

    convert_kernel<<<2048, 256, 0, stream>>>((const float4*)za, (const float4*)zb, z, rowsum);
    main_kernel<<<N_BLOCKS, 256, 0, stream>>>(z, rowsum, pospair);
    finalize_kernel<<<1, 256, 0, stream>>>(rowsum, pospair, out);
}